// Round 6
// baseline (100.437 us; speedup 1.0000x reference)
//
#include <hip/hip_runtime.h>
#include <hip/hip_bf16.h>
#include <math.h>

#define DDIM 200
#define D4   50
#define CCH  50
#define NREL 237
#define MAXE 16
#define MAXR 32          // 2*MAXE rows (src/tail interleaved)
#define NT   256
#define KT   7           // K tiles of 32 -> 224 (200 real, rest zero-padded)
#define NTREAL 13        // N tiles of 16 -> 208 >= 200

typedef __attribute__((ext_vector_type(8))) short bf16x8;
typedef __attribute__((ext_vector_type(4))) float f32x4;

__device__ __forceinline__ ushort f2bf(float x) {
    __hip_bfloat16 h = __float2bfloat16(x);   // RNE
    return *reinterpret_cast<ushort*>(&h);
}

// ---------- Kernel 1: counting sort by relation + balanced chunk emission ----------
__global__ __launch_bounds__(1024) void relsort_kernel(
    const int* __restrict__ bi, int B, int nblk,
    int* __restrict__ perm, int* __restrict__ blk_r,
    int* __restrict__ blk_start, int* __restrict__ blk_cnt)
{
    __shared__ int hist[NREL];
    __shared__ int offs[NREL];
    __shared__ int wsum[16], wsum2[16];
    const int tid  = threadIdx.x;
    const int lane = tid & 63;
    const int w    = tid >> 6;

    if (tid < NREL) hist[tid] = 0;
    __syncthreads();
    for (int i = tid; i < B; i += 1024)
        atomicAdd(&hist[bi[i * 3 + 1]], 1);
    __syncthreads();

    const int v  = (tid < NREL) ? hist[tid] : 0;
    const int v2 = (tid < NREL) ? (v + MAXE - 1) / MAXE : 0;
    int s = v, s2 = v2;
    #pragma unroll
    for (int off = 1; off < 64; off <<= 1) {
        const int u  = __shfl_up(s,  off, 64);
        const int u2 = __shfl_up(s2, off, 64);
        if (lane >= off) { s += u; s2 += u2; }
    }
    if (lane == 63) { wsum[w] = s; wsum2[w] = s2; }
    __syncthreads();
    int base = 0, base2 = 0;
    for (int i = 0; i < w; ++i) { base += wsum[i]; base2 += wsum2[i]; }
    const int my_off  = base  + s  - v;
    const int my_boff = base2 + s2 - v2;
    if (tid < NREL) offs[tid] = my_off;
    __syncthreads();

    for (int i = tid; i < nblk; i += 1024) blk_cnt[i] = 0;
    if (tid < NREL && v > 0) {
        const int nb = (v + MAXE - 1) / MAXE;
        const int cb = v / nb, ext = v - cb * nb;
        int pos = my_off;
        for (int j = 0; j < nb; ++j) {
            const int c = cb + (j < ext ? 1 : 0);
            blk_r[my_boff + j]     = tid;
            blk_start[my_boff + j] = pos;
            blk_cnt[my_boff + j]   = c;
            pos += c;
        }
    }
    __syncthreads();
    for (int i = tid; i < B; i += 1024) {
        const int pos = atomicAdd(&offs[bi[i * 3 + 1]], 1);
        perm[pos] = i;
    }
}

// ---------- Kernel 2: MFMA grouped-GEMM matvec + fused tanh/conv/relu/fc ----------
__global__ __launch_bounds__(NT) void spkbgat_mfma_kernel(
    const int*   __restrict__ bi,
    const float* __restrict__ ent,
    const float* __restrict__ rel_emb,
    const float* __restrict__ W,
    const float* __restrict__ conv_w,
    const float* __restrict__ conv_b,
    const float* __restrict__ fc_w,
    const float* __restrict__ fc_b,
    const int*   __restrict__ perm,
    const int*   __restrict__ blk_r,
    const int*   __restrict__ blk_start,
    const int*   __restrict__ blk_cnt,
    int nblk,
    float*       __restrict__ out)
{
    // big: first holds A (bf16 fragment layout, 14336 B); after the MFMA loop it
    // is reused as Osh = f32 [MAXR][204] (26112 B) holding tanh'd se/te rows.
    __shared__ __align__(16) unsigned char big[MAXR * 204 * 4];
    __shared__ __align__(16) float4 rl4[D4];
    __shared__ __align__(16) float  cwb[CCH][4];   // {w0,w1,w2,b}
    __shared__ int eid_lds[MAXR];
    __shared__ int bix_lds[MAXE];

    ushort* Ash = (ushort*)big;   // A[ktkg 0..27][row 0..31][8 bf16]
    float*  Osh = (float*)big;    // [row][204] f32

    const int tid  = threadIdx.x;
    const int w    = tid >> 6;
    const int lane = tid & 63;
    const int l16  = lane & 15;
    const int kg   = lane >> 4;    // k-group 0..3 within K=32

    // bijective XCD-chunked swizzle (same-relation chunks share an XCD L2)
    const int bid = blockIdx.x;
    const int q = nblk >> 3, rmd = nblk & 7;
    const int xcd = bid & 7, idx = bid >> 3;
    const int gidx = (xcd < rmd ? xcd * (q + 1) : rmd * (q + 1) + (xcd - rmd) * q) + idx;

    const int cnt = blk_cnt[gidx];
    if (cnt == 0) return;   // block-uniform: safe before barriers

    const int r     = blk_r[gidx];
    const int start = blk_start[gidx];
    const int rows  = 2 * cnt;

    // ---- small stages ----
    if (tid < CCH) {
        cwb[tid][0] = conv_w[tid * 3 + 0];
        cwb[tid][1] = conv_w[tid * 3 + 1];
        cwb[tid][2] = conv_w[tid * 3 + 2];
        cwb[tid][3] = conv_b[tid];
    }
    if (tid < D4) rl4[tid] = ((const float4*)rel_emb)[r * D4 + tid];
    if (tid < MAXE) {
        const int b = (tid < cnt) ? perm[start + tid] : -1;
        bix_lds[tid] = b;
        const int bb = (b >= 0) ? b : 0;
        eid_lds[2 * tid]     = bi[3 * bb + 0];   // head
        eid_lds[2 * tid + 1] = bi[3 * bb + 2];   // tail
    }
    __syncthreads();

    // ---- A stage: 28 ktkg-groups x 32 rows, one b128 LDS write per unit ----
    for (int u = tid; u < 28 * 32; u += NT) {
        const int row = u & 31, ktkg = u >> 5;       // k0 = 8*ktkg
        uint4 pk = {0u, 0u, 0u, 0u};
        if (ktkg < 25 && row < rows) {               // 25*8 = 200 real k's
            const float* xp = ent + (size_t)eid_lds[row] * DDIM + ktkg * 8;
            const float4 x0 = *(const float4*)xp;
            const float4 x1 = *(const float4*)(xp + 4);
            pk.x = (uint)f2bf(x0.x) | ((uint)f2bf(x0.y) << 16);
            pk.y = (uint)f2bf(x0.z) | ((uint)f2bf(x0.w) << 16);
            pk.z = (uint)f2bf(x1.x) | ((uint)f2bf(x1.y) << 16);
            pk.w = (uint)f2bf(x1.z) | ((uint)f2bf(x1.w) << 16);
        }
        *(uint4*)&Ash[u * 8] = pk;
    }
    __syncthreads();

    // ---- MFMA loop (barrier-free): wave w owns N-tiles {w, w+4, w+8, w+12<13} ----
    const int nslots = (w == 0) ? 4 : 3;
    const float* __restrict__ Wr = W + (size_t)r * (DDIM * DDIM);
    f32x4 acc[2][4];
    #pragma unroll
    for (int mt = 0; mt < 2; ++mt)
        #pragma unroll
        for (int s = 0; s < 4; ++s)
            acc[mt][s] = (f32x4){0.f, 0.f, 0.f, 0.f};

    for (int kt = 0; kt < KT; ++kt) {
        // A fragments: lane holds A[row=l16(+16)][k = kt*32+8*kg .. +8)
        const int abase = ((kt * 4 + kg) * 32 + l16) * 8;
        const bf16x8 a0 = *(const bf16x8*)&Ash[abase];
        const bf16x8 a1 = *(const bf16x8*)&Ash[abase + 16 * 8];
        const int k0 = kt * 32 + kg * 8;
        #pragma unroll
        for (int s = 0; s < 4; ++s) {
            if (s < nslots) {
                const int col = (w + 4 * s) * 16 + l16;
                // B fragment: lane holds W[k0..k0+8)[col]; 16 lanes -> 64B coalesced
                bf16x8 bf;
                #pragma unroll
                for (int j = 0; j < 8; ++j) {
                    const int k = k0 + j;
                    const float v = (k < DDIM && col < DDIM) ? Wr[k * DDIM + col] : 0.f;
                    bf[j] = (short)f2bf(v);
                }
                acc[0][s] = __builtin_amdgcn_mfma_f32_16x16x32_bf16(a0, bf, acc[0][s], 0, 0, 0);
                acc[1][s] = __builtin_amdgcn_mfma_f32_16x16x32_bf16(a1, bf, acc[1][s], 0, 0, 0);
            }
        }
    }
    __syncthreads();   // all A reads done before Osh overwrites the region

    // ---- tanh + write se/te rows: D[row=(kg*4+v)][col=l16] per 16x16 tile ----
    #pragma unroll
    for (int mt = 0; mt < 2; ++mt) {
        #pragma unroll
        for (int s = 0; s < 4; ++s) {
            if (s < nslots) {
                const int gcol = (w + 4 * s) * 16 + l16;
                if (gcol < DDIM) {
                    #pragma unroll
                    for (int v = 0; v < 4; ++v) {
                        const int grow = mt * 16 + kg * 4 + v;
                        if (grow < rows)
                            Osh[grow * 204 + gcol] = tanhf(acc[mt][s][v]);
                    }
                }
            }
        }
    }
    __syncthreads();

    // ---- epilogue: lane owns d4-slice; se/te/rl in regs across the c-loop ----
    float sums[4] = {0.f, 0.f, 0.f, 0.f};
    if (lane < D4) {
        const float4 rv = rl4[lane];
        float4 se[4], te[4];
        #pragma unroll
        for (int s2 = 0; s2 < 4; ++s2) {
            const int e = w + 4 * s2;
            if (e < cnt) {
                se[s2] = *(const float4*)&Osh[(2 * e) * 204 + 4 * lane];
                te[s2] = *(const float4*)&Osh[(2 * e + 1) * 204 + 4 * lane];
            } else {
                se[s2] = (float4){0.f, 0.f, 0.f, 0.f};
                te[s2] = (float4){0.f, 0.f, 0.f, 0.f};
            }
        }
        for (int c = 0; c < CCH; ++c) {
            const float4 cw  = *(const float4*)&cwb[c][0];       // LDS broadcast
            const float4 fc4 = ((const float4*)fc_w)[c * D4 + lane];
            #pragma unroll
            for (int s2 = 0; s2 < 4; ++s2) {
                if (w + 4 * s2 < cnt) {   // wave-uniform guard
                    const float v0 = fmaf(cw.x, se[s2].x, fmaf(cw.y, rv.x, fmaf(cw.z, te[s2].x, cw.w)));
                    const float v1 = fmaf(cw.x, se[s2].y, fmaf(cw.y, rv.y, fmaf(cw.z, te[s2].y, cw.w)));
                    const float v2 = fmaf(cw.x, se[s2].z, fmaf(cw.y, rv.z, fmaf(cw.z, te[s2].z, cw.w)));
                    const float v3 = fmaf(cw.x, se[s2].w, fmaf(cw.y, rv.w, fmaf(cw.z, te[s2].w, cw.w)));
                    sums[s2] = fmaf(fmaxf(v0, 0.f), fc4.x, sums[s2]);
                    sums[s2] = fmaf(fmaxf(v1, 0.f), fc4.y, sums[s2]);
                    sums[s2] = fmaf(fmaxf(v2, 0.f), fc4.z, sums[s2]);
                    sums[s2] = fmaf(fmaxf(v3, 0.f), fc4.w, sums[s2]);
                }
            }
        }
    }
    #pragma unroll
    for (int s2 = 0; s2 < 4; ++s2) {
        float v = sums[s2];
        #pragma unroll
        for (int off = 32; off; off >>= 1)
            v += __shfl_down(v, off, 64);
        if (lane == 0) {
            const int e = w + 4 * s2;
            if (e < cnt) out[bix_lds[e]] = v + fc_b[0];
        }
    }
}

extern "C" void kernel_launch(void* const* d_in, const int* in_sizes, int n_in,
                              void* d_out, int out_size, void* d_ws, size_t ws_size,
                              hipStream_t stream) {
    const int*   bi      = (const int*)  d_in[0];
    const float* ent     = (const float*)d_in[1];
    const float* rel_emb = (const float*)d_in[2];
    const float* W       = (const float*)d_in[3];
    const float* conv_w  = (const float*)d_in[4];
    const float* conv_b  = (const float*)d_in[5];
    const float* fc_w    = (const float*)d_in[6];
    const float* fc_b    = (const float*)d_in[7];
    float*       out     = (float*)d_out;

    const int B    = in_sizes[0] / 3;                  // 8192
    const int nblk = NREL + (B + MAXE - 1) / MAXE;     // 749 worst-case chunks

    int* perm      = (int*)d_ws;
    int* blk_r     = perm + B;
    int* blk_start = blk_r + nblk;
    int* blk_cnt   = blk_start + nblk;

    relsort_kernel<<<1, 1024, 0, stream>>>(bi, B, nblk, perm, blk_r, blk_start, blk_cnt);
    spkbgat_mfma_kernel<<<nblk, NT, 0, stream>>>(
        bi, ent, rel_emb, W, conv_w, conv_b, fc_w, fc_b,
        perm, blk_r, blk_start, blk_cnt, nblk, out);
}

// Round 7
// 58.345 us; speedup vs baseline: 1.7214x; 1.7214x over previous
//
#include <hip/hip_runtime.h>
#include <hip/hip_bf16.h>
#include <math.h>

#define DDIM 200
#define D4   50
#define CCH  50
#define NREL 237
#define MAXE 8
#define MAXR 16          // 2*MAXE rows (src/tail interleaved)
#define NT   256
#define KT   7           // K tiles of 32 -> 224 (200 real, zero-padded)
#define NTI  13          // N tiles of 16 -> 208 >= 200
#define KTKG 28          // (kt,kg) pairs: k0 = ktkg*8
#define NCOLP 208        // padded col count in packed W
#define OSTRIDE 204
#define PACK_UNITS (NREL * KTKG * NCOLP)

typedef __attribute__((ext_vector_type(8))) short bf16x8;
typedef __attribute__((ext_vector_type(4))) float f32x4;

__device__ __forceinline__ uint f2bf(float x) {
    __hip_bfloat16 h = __float2bfloat16(x);   // RNE
    return (uint)*reinterpret_cast<ushort*>(&h);
}

// ---------- Kernel 0: pack W -> bf16 fragment layout Wpk[r][ktkg][col][8] ----------
__global__ __launch_bounds__(256) void packW_kernel(
    const float* __restrict__ W, ushort* __restrict__ Wpk)
{
    const int u = blockIdx.x * 256 + threadIdx.x;
    if (u >= PACK_UNITS) return;
    const int col  = u % NCOLP;
    const int rk   = u / NCOLP;
    const int ktkg = rk % KTKG;
    const int r    = rk / KTKG;
    const int k0   = ktkg * 8;
    uint4 pk = {0u, 0u, 0u, 0u};
    if (col < DDIM) {
        const float* base = W + (size_t)r * DDIM * DDIM + col;
        uint vv[8];
        #pragma unroll
        for (int j = 0; j < 8; ++j) {
            const int k = k0 + j;
            vv[j] = (k < DDIM) ? f2bf(base[(size_t)k * DDIM]) : 0u;  // coalesced per j
        }
        pk.x = vv[0] | (vv[1] << 16);
        pk.y = vv[2] | (vv[3] << 16);
        pk.z = vv[4] | (vv[5] << 16);
        pk.w = vv[6] | (vv[7] << 16);
    }
    *(uint4*)&Wpk[(size_t)u * 8] = pk;   // consecutive threads -> contiguous 16B
}

// ---------- Kernel 1: counting sort by relation + balanced chunk emission ----------
__global__ __launch_bounds__(1024) void relsort_kernel(
    const int* __restrict__ bi, int B, int nblk,
    int* __restrict__ perm, int* __restrict__ blk_r,
    int* __restrict__ blk_start, int* __restrict__ blk_cnt)
{
    __shared__ int hist[NREL];
    __shared__ int offs[NREL];
    __shared__ int wsum[16], wsum2[16];
    const int tid  = threadIdx.x;
    const int lane = tid & 63;
    const int w    = tid >> 6;

    if (tid < NREL) hist[tid] = 0;
    __syncthreads();
    for (int i = tid; i < B; i += 1024)
        atomicAdd(&hist[bi[i * 3 + 1]], 1);
    __syncthreads();

    const int v  = (tid < NREL) ? hist[tid] : 0;
    const int v2 = (tid < NREL) ? (v + MAXE - 1) / MAXE : 0;
    int s = v, s2 = v2;
    #pragma unroll
    for (int off = 1; off < 64; off <<= 1) {
        const int u  = __shfl_up(s,  off, 64);
        const int u2 = __shfl_up(s2, off, 64);
        if (lane >= off) { s += u; s2 += u2; }
    }
    if (lane == 63) { wsum[w] = s; wsum2[w] = s2; }
    __syncthreads();
    int base = 0, base2 = 0;
    for (int i = 0; i < w; ++i) { base += wsum[i]; base2 += wsum2[i]; }
    const int my_off  = base  + s  - v;
    const int my_boff = base2 + s2 - v2;
    if (tid < NREL) offs[tid] = my_off;
    __syncthreads();

    for (int i = tid; i < nblk; i += 1024) blk_cnt[i] = 0;
    if (tid < NREL && v > 0) {
        const int nb = (v + MAXE - 1) / MAXE;
        const int cb = v / nb, ext = v - cb * nb;
        int pos = my_off;
        for (int j = 0; j < nb; ++j) {
            const int c = cb + (j < ext ? 1 : 0);
            blk_r[my_boff + j]     = tid;
            blk_start[my_boff + j] = pos;
            blk_cnt[my_boff + j]   = c;
            pos += c;
        }
    }
    __syncthreads();
    for (int i = tid; i < B; i += 1024) {
        const int pos = atomicAdd(&offs[bi[i * 3 + 1]], 1);
        perm[pos] = i;
    }
}

// ---------- Kernel 2: MFMA grouped-GEMM matvec + fused tanh/conv/relu/fc ----------
template <bool PACKED>
__global__ __launch_bounds__(NT) void spkbgat_mfma_kernel(
    const int*   __restrict__ bi,
    const float* __restrict__ ent,
    const float* __restrict__ rel_emb,
    const float* __restrict__ W,
    const ushort* __restrict__ Wpk,
    const float* __restrict__ conv_w,
    const float* __restrict__ conv_b,
    const float* __restrict__ fc_w,
    const float* __restrict__ fc_b,
    const int*   __restrict__ perm,
    const int*   __restrict__ blk_r,
    const int*   __restrict__ blk_start,
    const int*   __restrict__ blk_cnt,
    int nblk,
    float*       __restrict__ out)
{
    __shared__ __align__(16) ushort Ash[KTKG * MAXR * 8];   // 7 KB, fragment layout
    __shared__ __align__(16) float  Osh[MAXR][OSTRIDE];     // 13 KB tanh'd se/te
    __shared__ __align__(16) float4 rl4[D4];
    __shared__ __align__(16) float  cwb[CCH][4];            // {w0,w1,w2,b}
    __shared__ int eid_lds[MAXR];
    __shared__ int bix_lds[MAXE];

    const int tid  = threadIdx.x;
    const int w    = tid >> 6;
    const int lane = tid & 63;
    const int l16  = lane & 15;
    const int kg   = lane >> 4;

    // bijective XCD-chunked swizzle (same-relation chunks share an XCD L2)
    const int bid = blockIdx.x;
    const int q = nblk >> 3, rmd = nblk & 7;
    const int xcd = bid & 7, idx = bid >> 3;
    const int gidx = (xcd < rmd ? xcd * (q + 1) : rmd * (q + 1) + (xcd - rmd) * q) + idx;

    const int cnt = blk_cnt[gidx];
    if (cnt == 0) return;   // block-uniform: safe before barriers

    const int r     = blk_r[gidx];
    const int start = blk_start[gidx];
    const int rows  = 2 * cnt;

    // ---- small stages ----
    if (tid < CCH) {
        cwb[tid][0] = conv_w[tid * 3 + 0];
        cwb[tid][1] = conv_w[tid * 3 + 1];
        cwb[tid][2] = conv_w[tid * 3 + 2];
        cwb[tid][3] = conv_b[tid];
    }
    if (tid < D4) rl4[tid] = ((const float4*)rel_emb)[r * D4 + tid];
    if (tid < MAXE) {
        const int b = (tid < cnt) ? perm[start + tid] : -1;
        bix_lds[tid] = b;
        const int bb = (b >= 0) ? b : 0;
        eid_lds[2 * tid]     = bi[3 * bb + 0];   // head
        eid_lds[2 * tid + 1] = bi[3 * bb + 2];   // tail
    }
    __syncthreads();

    // ---- A stage: 28 ktkg-groups x 16 rows -> one b128 LDS write per unit ----
    for (int u = tid; u < KTKG * MAXR; u += NT) {
        const int row  = u & (MAXR - 1);
        const int ktkg = u >> 4;
        uint4 pk = {0u, 0u, 0u, 0u};
        if (ktkg < 25 && row < rows) {               // 25*8 = 200 real k's
            const float* xp = ent + (size_t)eid_lds[row] * DDIM + ktkg * 8;
            const float4 x0 = *(const float4*)xp;
            const float4 x1 = *(const float4*)(xp + 4);
            pk.x = f2bf(x0.x) | (f2bf(x0.y) << 16);
            pk.y = f2bf(x0.z) | (f2bf(x0.w) << 16);
            pk.z = f2bf(x1.x) | (f2bf(x1.y) << 16);
            pk.w = f2bf(x1.z) | (f2bf(x1.w) << 16);
        }
        *(uint4*)&Ash[u * 8] = pk;
    }
    __syncthreads();

    // ---- MFMA loop (barrier-free): wave w owns N-tiles {w, w+4, w+8, w+12<13} ----
    const int nslots = (w == 0) ? 4 : 3;
    const float*  __restrict__ Wr = W + (size_t)r * DDIM * DDIM;
    const ushort* __restrict__ Wp = Wpk + (size_t)r * KTKG * NCOLP * 8;
    f32x4 acc[4];
    #pragma unroll
    for (int s = 0; s < 4; ++s) acc[s] = (f32x4){0.f, 0.f, 0.f, 0.f};

    for (int kt = 0; kt < KT; ++kt) {
        const int ktkg = kt * 4 + kg;
        const bf16x8 a0 = *(const bf16x8*)&Ash[(ktkg * MAXR + l16) * 8];
        #pragma unroll
        for (int s = 0; s < 4; ++s) {
            if (s < nslots) {
                const int col = (w + 4 * s) * 16 + l16;
                bf16x8 bf;
                if (PACKED) {
                    // 16 lanes x 16B = 256B contiguous per quarter-wave
                    bf = *(const bf16x8*)&Wp[((size_t)ktkg * NCOLP + col) * 8];
                } else {
                    const int k0 = ktkg * 8;
                    #pragma unroll
                    for (int j = 0; j < 8; ++j) {
                        const int k = k0 + j;
                        const float v = (k < DDIM && col < DDIM) ? Wr[k * DDIM + col] : 0.f;
                        bf[j] = (short)f2bf(v);
                    }
                }
                acc[s] = __builtin_amdgcn_mfma_f32_16x16x32_bf16(a0, bf, acc[s], 0, 0, 0);
            }
        }
    }

    // ---- tanh + write se/te rows: D[row=kg*4+v][col=l16] per 16x16 tile ----
    #pragma unroll
    for (int s = 0; s < 4; ++s) {
        if (s < nslots) {
            const int gcol = (w + 4 * s) * 16 + l16;
            if (gcol < DDIM) {
                #pragma unroll
                for (int v = 0; v < 4; ++v) {
                    const int grow = kg * 4 + v;
                    if (grow < rows)
                        Osh[grow][gcol] = tanhf(acc[s][v]);
                }
            }
        }
    }
    __syncthreads();

    // ---- epilogue: lane owns d4-slice; wave w owns elements {w, w+4} ----
    float sums[2] = {0.f, 0.f};
    if (lane < D4) {
        const float4 rv = rl4[lane];
        float4 se[2], te[2];
        #pragma unroll
        for (int s2 = 0; s2 < 2; ++s2) {
            const int e = w + 4 * s2;
            if (e < cnt) {
                se[s2] = *(const float4*)&Osh[2 * e][4 * lane];
                te[s2] = *(const float4*)&Osh[2 * e + 1][4 * lane];
            } else {
                se[s2] = (float4){0.f, 0.f, 0.f, 0.f};
                te[s2] = (float4){0.f, 0.f, 0.f, 0.f};
            }
        }
        for (int c = 0; c < CCH; ++c) {
            const float4 cw  = *(const float4*)&cwb[c][0];
            const float4 fc4 = ((const float4*)fc_w)[c * D4 + lane];
            #pragma unroll
            for (int s2 = 0; s2 < 2; ++s2) {
                if (w + 4 * s2 < cnt) {   // wave-uniform guard
                    const float v0 = fmaf(cw.x, se[s2].x, fmaf(cw.y, rv.x, fmaf(cw.z, te[s2].x, cw.w)));
                    const float v1 = fmaf(cw.x, se[s2].y, fmaf(cw.y, rv.y, fmaf(cw.z, te[s2].y, cw.w)));
                    const float v2 = fmaf(cw.x, se[s2].z, fmaf(cw.y, rv.z, fmaf(cw.z, te[s2].z, cw.w)));
                    const float v3 = fmaf(cw.x, se[s2].w, fmaf(cw.y, rv.w, fmaf(cw.z, te[s2].w, cw.w)));
                    sums[s2] = fmaf(fmaxf(v0, 0.f), fc4.x, sums[s2]);
                    sums[s2] = fmaf(fmaxf(v1, 0.f), fc4.y, sums[s2]);
                    sums[s2] = fmaf(fmaxf(v2, 0.f), fc4.z, sums[s2]);
                    sums[s2] = fmaf(fmaxf(v3, 0.f), fc4.w, sums[s2]);
                }
            }
        }
    }
    #pragma unroll
    for (int s2 = 0; s2 < 2; ++s2) {
        float v = sums[s2];
        #pragma unroll
        for (int off = 32; off; off >>= 1)
            v += __shfl_down(v, off, 64);
        if (lane == 0) {
            const int e = w + 4 * s2;
            if (e < cnt) out[bix_lds[e]] = v + fc_b[0];
        }
    }
}

extern "C" void kernel_launch(void* const* d_in, const int* in_sizes, int n_in,
                              void* d_out, int out_size, void* d_ws, size_t ws_size,
                              hipStream_t stream) {
    const int*   bi      = (const int*)  d_in[0];
    const float* ent     = (const float*)d_in[1];
    const float* rel_emb = (const float*)d_in[2];
    const float* W       = (const float*)d_in[3];
    const float* conv_w  = (const float*)d_in[4];
    const float* conv_b  = (const float*)d_in[5];
    const float* fc_w    = (const float*)d_in[6];
    const float* fc_b    = (const float*)d_in[7];
    float*       out     = (float*)d_out;

    const int B    = in_sizes[0] / 3;                  // 8192
    const int nblk = NREL + (B + MAXE - 1) / MAXE;     // 1261 worst-case chunks

    int* perm      = (int*)d_ws;
    int* blk_r     = perm + B;
    int* blk_start = blk_r + nblk;
    int* blk_cnt   = blk_start + nblk;

    const size_t meta_bytes = (size_t)(B + 3 * nblk) * sizeof(int);
    const size_t pk_off     = (meta_bytes + 255) & ~(size_t)255;
    const size_t need       = pk_off + (size_t)PACK_UNITS * 16;
    const bool   use_packed = (ws_size >= need);
    ushort* Wpk = (ushort*)((char*)d_ws + pk_off);

    if (use_packed) {
        packW_kernel<<<(PACK_UNITS + 255) / 256, 256, 0, stream>>>(W, Wpk);
    }
    relsort_kernel<<<1, 1024, 0, stream>>>(bi, B, nblk, perm, blk_r, blk_start, blk_cnt);
    if (use_packed) {
        spkbgat_mfma_kernel<true><<<nblk, NT, 0, stream>>>(
            bi, ent, rel_emb, W, Wpk, conv_w, conv_b, fc_w, fc_b,
            perm, blk_r, blk_start, blk_cnt, nblk, out);
    } else {
        spkbgat_mfma_kernel<false><<<nblk, NT, 0, stream>>>(
            bi, ent, rel_emb, W, Wpk, conv_w, conv_b, fc_w, fc_b,
            perm, blk_r, blk_start, blk_cnt, nblk, out);
    }
}

// Round 8
// 57.415 us; speedup vs baseline: 1.7493x; 1.0162x over previous
//
#include <hip/hip_runtime.h>
#include <hip/hip_bf16.h>
#include <math.h>

#define DDIM 200
#define D4   50
#define CCH  50
#define NREL 237
#define MAXE 4           // elements per chunk/block
#define MAXR 8           // 2*MAXE data rows
#define AROWS 16         // M-tile rows (MFMA shape)
#define NT   256
#define KT   7           // K tiles of 32 -> 224 (200 real, zero-padded)
#define KTKG 28          // (kt,kg) pairs: k0 = ktkg*8
#define NCOLP 208        // padded col count in packed W
#define OSTRIDE 204
#define PACK_UNITS (NREL * KTKG * NCOLP)

typedef __attribute__((ext_vector_type(8))) short bf16x8;
typedef __attribute__((ext_vector_type(4))) float f32x4;

__device__ __forceinline__ uint f2bf(float x) {
    __hip_bfloat16 h = __float2bfloat16(x);   // RNE
    return (uint)*reinterpret_cast<ushort*>(&h);
}

__device__ __forceinline__ float fast_tanh(float x) {
    const float xc = fminf(fmaxf(x, -20.f), 20.f);     // avoid inf/inf
    const float e  = __expf(2.f * xc);                 // v_exp_f32 path
    return 1.f - __fdividef(2.f, e + 1.f);             // rcp-based divide
}

// ---------- Kernel 1: block 0 = relation sort + chunk emission; blocks 1.. = W pack ----------
__global__ __launch_bounds__(1024) void prep_kernel(
    const float* __restrict__ W, ushort* __restrict__ Wpk, int do_pack,
    const int* __restrict__ bi, int B, int nblk,
    int* __restrict__ perm, int* __restrict__ blk_r,
    int* __restrict__ blk_start, int* __restrict__ blk_cnt)
{
    const int tid = threadIdx.x;

    if (blockIdx.x != 0) {
        // ---- pack W -> bf16 fragment layout Wpk[r][ktkg][col][8] ----
        if (!do_pack) return;
        const int u = (blockIdx.x - 1) * 1024 + tid;
        if (u >= PACK_UNITS) return;
        const int col  = u % NCOLP;
        const int rk   = u / NCOLP;
        const int ktkg = rk % KTKG;
        const int r    = rk / KTKG;
        const int k0   = ktkg * 8;
        uint4 pk = {0u, 0u, 0u, 0u};
        if (col < DDIM) {
            const float* base = W + (size_t)r * DDIM * DDIM + col;
            uint vv[8];
            #pragma unroll
            for (int j = 0; j < 8; ++j) {
                const int k = k0 + j;
                vv[j] = (k < DDIM) ? f2bf(base[(size_t)k * DDIM]) : 0u;  // coalesced per j
            }
            pk.x = vv[0] | (vv[1] << 16);
            pk.y = vv[2] | (vv[3] << 16);
            pk.z = vv[4] | (vv[5] << 16);
            pk.w = vv[6] | (vv[7] << 16);
        }
        *(uint4*)&Wpk[(size_t)u * 8] = pk;
        return;
    }

    // ---- block 0: counting sort + balanced chunk emission ----
    __shared__ int hist[NREL];
    __shared__ int offs[NREL];
    __shared__ int wsum[16], wsum2[16];
    const int lane = tid & 63;
    const int w    = tid >> 6;

    if (tid < NREL) hist[tid] = 0;
    __syncthreads();
    for (int i = tid; i < B; i += 1024)
        atomicAdd(&hist[bi[i * 3 + 1]], 1);
    __syncthreads();

    const int v  = (tid < NREL) ? hist[tid] : 0;
    const int v2 = (tid < NREL) ? (v + MAXE - 1) / MAXE : 0;
    int s = v, s2 = v2;
    #pragma unroll
    for (int off = 1; off < 64; off <<= 1) {
        const int u  = __shfl_up(s,  off, 64);
        const int u2 = __shfl_up(s2, off, 64);
        if (lane >= off) { s += u; s2 += u2; }
    }
    if (lane == 63) { wsum[w] = s; wsum2[w] = s2; }
    __syncthreads();
    int base = 0, base2 = 0;
    for (int i = 0; i < w; ++i) { base += wsum[i]; base2 += wsum2[i]; }
    const int my_off  = base  + s  - v;
    const int my_boff = base2 + s2 - v2;
    if (tid < NREL) offs[tid] = my_off;
    __syncthreads();

    for (int i = tid; i < nblk; i += 1024) blk_cnt[i] = 0;
    if (tid < NREL && v > 0) {
        const int nb = (v + MAXE - 1) / MAXE;
        const int cb = v / nb, ext = v - cb * nb;
        int pos = my_off;
        for (int j = 0; j < nb; ++j) {
            const int c = cb + (j < ext ? 1 : 0);
            blk_r[my_boff + j]     = tid;
            blk_start[my_boff + j] = pos;
            blk_cnt[my_boff + j]   = c;
            pos += c;
        }
    }
    __syncthreads();
    for (int i = tid; i < B; i += 1024) {
        const int pos = atomicAdd(&offs[bi[i * 3 + 1]], 1);
        perm[pos] = i;
    }
}

// ---------- Kernel 2: MFMA grouped-GEMM matvec + fused tanh/conv/relu/fc ----------
template <bool PACKED>
__global__ __launch_bounds__(NT) void spkbgat_mfma_kernel(
    const int*   __restrict__ bi,
    const float* __restrict__ ent,
    const float* __restrict__ rel_emb,
    const float* __restrict__ W,
    const ushort* __restrict__ Wpk,
    const float* __restrict__ conv_w,
    const float* __restrict__ conv_b,
    const float* __restrict__ fc_w,
    const float* __restrict__ fc_b,
    const int*   __restrict__ perm,
    const int*   __restrict__ blk_r,
    const int*   __restrict__ blk_start,
    const int*   __restrict__ blk_cnt,
    int nblk,
    float*       __restrict__ out)
{
    __shared__ __align__(16) ushort Ash[KTKG * AROWS * 8];  // 7 KB, fragment layout
    __shared__ __align__(16) float  Osh[MAXR][OSTRIDE];     // 6.5 KB tanh'd se/te
    __shared__ __align__(16) float4 rl4[D4];
    __shared__ __align__(16) float  cwb[CCH][4];            // {w0,w1,w2,b}
    __shared__ int eid_lds[MAXR];
    __shared__ int bix_lds[MAXE];

    const int tid  = threadIdx.x;
    const int w    = tid >> 6;
    const int lane = tid & 63;
    const int l16  = lane & 15;
    const int kg   = lane >> 4;

    // bijective XCD-chunked swizzle (same-relation chunks share an XCD L2)
    const int bid = blockIdx.x;
    const int q = nblk >> 3, rmd = nblk & 7;
    const int xcd = bid & 7, idx = bid >> 3;
    const int gidx = (xcd < rmd ? xcd * (q + 1) : rmd * (q + 1) + (xcd - rmd) * q) + idx;

    const int cnt = blk_cnt[gidx];
    if (cnt == 0) return;   // block-uniform: safe before barriers

    const int r     = blk_r[gidx];
    const int start = blk_start[gidx];
    const int rows  = 2 * cnt;

    // ---- small stages ----
    if (tid < CCH) {
        cwb[tid][0] = conv_w[tid * 3 + 0];
        cwb[tid][1] = conv_w[tid * 3 + 1];
        cwb[tid][2] = conv_w[tid * 3 + 2];
        cwb[tid][3] = conv_b[tid];
    }
    if (tid < D4) rl4[tid] = ((const float4*)rel_emb)[r * D4 + tid];
    if (tid < MAXE) {
        const int b = (tid < cnt) ? perm[start + tid] : -1;
        bix_lds[tid] = b;
        const int bb = (b >= 0) ? b : 0;
        eid_lds[2 * tid]     = bi[3 * bb + 0];   // head
        eid_lds[2 * tid + 1] = bi[3 * bb + 2];   // tail
    }
    __syncthreads();

    // ---- A stage: 28 ktkg-groups x 16 A-rows -> one b128 LDS write per unit ----
    for (int u = tid; u < KTKG * AROWS; u += NT) {
        const int row  = u & (AROWS - 1);
        const int ktkg = u >> 4;
        uint4 pk = {0u, 0u, 0u, 0u};
        if (ktkg < 25 && row < rows) {               // 25*8 = 200 real k's
            const float* xp = ent + (size_t)eid_lds[row] * DDIM + ktkg * 8;
            const float4 x0 = *(const float4*)xp;
            const float4 x1 = *(const float4*)(xp + 4);
            pk.x = f2bf(x0.x) | (f2bf(x0.y) << 16);
            pk.y = f2bf(x0.z) | (f2bf(x0.w) << 16);
            pk.z = f2bf(x1.x) | (f2bf(x1.y) << 16);
            pk.w = f2bf(x1.z) | (f2bf(x1.w) << 16);
        }
        *(uint4*)&Ash[u * 8] = pk;
    }
    __syncthreads();

    // ---- MFMA loop (barrier-free): wave w owns N-tiles {w, w+4, w+8, w+12<13} ----
    const int nslots = (w == 0) ? 4 : 3;
    const float*  __restrict__ Wr = W + (size_t)r * DDIM * DDIM;
    const ushort* __restrict__ Wp = Wpk + (size_t)r * KTKG * NCOLP * 8;
    f32x4 acc[4];
    #pragma unroll
    for (int s = 0; s < 4; ++s) acc[s] = (f32x4){0.f, 0.f, 0.f, 0.f};

    for (int kt = 0; kt < KT; ++kt) {
        const int ktkg = kt * 4 + kg;
        const bf16x8 a0 = *(const bf16x8*)&Ash[(ktkg * AROWS + l16) * 8];
        #pragma unroll
        for (int s = 0; s < 4; ++s) {
            if (s < nslots) {
                const int col = (w + 4 * s) * 16 + l16;
                bf16x8 bf;
                if (PACKED) {
                    // 16 lanes x 16B = 256B contiguous per quarter-wave
                    bf = *(const bf16x8*)&Wp[((size_t)ktkg * NCOLP + col) * 8];
                } else {
                    const int k0 = ktkg * 8;
                    #pragma unroll
                    for (int j = 0; j < 8; ++j) {
                        const int k = k0 + j;
                        const float vv = (k < DDIM && col < DDIM) ? Wr[k * DDIM + col] : 0.f;
                        bf[j] = (short)f2bf(vv);
                    }
                }
                acc[s] = __builtin_amdgcn_mfma_f32_16x16x32_bf16(a0, bf, acc[s], 0, 0, 0);
            }
        }
    }

    // ---- tanh + write se/te rows: D[row=kg*4+v][col=l16] per 16x16 tile ----
    #pragma unroll
    for (int s = 0; s < 4; ++s) {
        if (s < nslots) {
            const int gcol = (w + 4 * s) * 16 + l16;
            if (gcol < DDIM) {
                #pragma unroll
                for (int v = 0; v < 4; ++v) {
                    const int grow = kg * 4 + v;
                    if (grow < rows)
                        Osh[grow][gcol] = fast_tanh(acc[s][v]);
                }
            }
        }
    }
    __syncthreads();

    // ---- epilogue: lane owns d4-slice; wave w owns element w ----
    float4 sumv = {0.f, 0.f, 0.f, 0.f};
    const bool live = (w < cnt);
    if (lane < D4 && live) {
        const float4 rv = rl4[lane];
        const float4 se = *(const float4*)&Osh[2 * w][4 * lane];
        const float4 te = *(const float4*)&Osh[2 * w + 1][4 * lane];
        for (int c = 0; c < CCH; ++c) {
            const float4 cw  = *(const float4*)&cwb[c][0];
            const float4 fc4 = ((const float4*)fc_w)[c * D4 + lane];
            const float v0 = fmaf(cw.x, se.x, fmaf(cw.y, rv.x, fmaf(cw.z, te.x, cw.w)));
            const float v1 = fmaf(cw.x, se.y, fmaf(cw.y, rv.y, fmaf(cw.z, te.y, cw.w)));
            const float v2 = fmaf(cw.x, se.z, fmaf(cw.y, rv.z, fmaf(cw.z, te.z, cw.w)));
            const float v3 = fmaf(cw.x, se.w, fmaf(cw.y, rv.w, fmaf(cw.z, te.w, cw.w)));
            sumv.x = fmaf(fmaxf(v0, 0.f), fc4.x, sumv.x);   // 4 independent chains
            sumv.y = fmaf(fmaxf(v1, 0.f), fc4.y, sumv.y);
            sumv.z = fmaf(fmaxf(v2, 0.f), fc4.z, sumv.z);
            sumv.w = fmaf(fmaxf(v3, 0.f), fc4.w, sumv.w);
        }
    }
    float sum = (sumv.x + sumv.y) + (sumv.z + sumv.w);
    #pragma unroll
    for (int off = 32; off; off >>= 1)
        sum += __shfl_down(sum, off, 64);
    if (lane == 0 && live) out[bix_lds[w]] = sum + fc_b[0];
}

extern "C" void kernel_launch(void* const* d_in, const int* in_sizes, int n_in,
                              void* d_out, int out_size, void* d_ws, size_t ws_size,
                              hipStream_t stream) {
    const int*   bi      = (const int*)  d_in[0];
    const float* ent     = (const float*)d_in[1];
    const float* rel_emb = (const float*)d_in[2];
    const float* W       = (const float*)d_in[3];
    const float* conv_w  = (const float*)d_in[4];
    const float* conv_b  = (const float*)d_in[5];
    const float* fc_w    = (const float*)d_in[6];
    const float* fc_b    = (const float*)d_in[7];
    float*       out     = (float*)d_out;

    const int B    = in_sizes[0] / 3;                  // 8192
    const int nblk = NREL + (B + MAXE - 1) / MAXE;     // 2285 worst-case chunks

    int* perm      = (int*)d_ws;
    int* blk_r     = perm + B;
    int* blk_start = blk_r + nblk;
    int* blk_cnt   = blk_start + nblk;

    const size_t meta_bytes = (size_t)(B + 3 * nblk) * sizeof(int);
    const size_t pk_off     = (meta_bytes + 255) & ~(size_t)255;
    const size_t need       = pk_off + (size_t)PACK_UNITS * 16;
    const bool   use_packed = (ws_size >= need);
    ushort* Wpk = (ushort*)((char*)d_ws + pk_off);

    const int prep_blocks = 1 + (PACK_UNITS + 1023) / 1024;   // block 0 = sort
    prep_kernel<<<prep_blocks, 1024, 0, stream>>>(
        W, Wpk, use_packed ? 1 : 0, bi, B, nblk, perm, blk_r, blk_start, blk_cnt);

    if (use_packed) {
        spkbgat_mfma_kernel<true><<<nblk, NT, 0, stream>>>(
            bi, ent, rel_emb, W, Wpk, conv_w, conv_b, fc_w, fc_b,
            perm, blk_r, blk_start, blk_cnt, nblk, out);
    } else {
        spkbgat_mfma_kernel<false><<<nblk, NT, 0, stream>>>(
            bi, ent, rel_emb, W, Wpk, conv_w, conv_b, fc_w, fc_b,
            perm, blk_r, blk_start, blk_cnt, nblk, out);
    }
}